// Round 1
// baseline (220.161 us; speedup 1.0000x reference)
//
#include <hip/hip_runtime.h>

#define BN_EPS 1e-5f

typedef unsigned short u16;
typedef __bf16 bf16x8 __attribute__((ext_vector_type(8)));
typedef float floatx4 __attribute__((ext_vector_type(4)));
typedef u16 u16x4 __attribute__((ext_vector_type(4)));
typedef u16 u16x8 __attribute__((ext_vector_type(8)));

__device__ __forceinline__ u16 f2bf(float f) {
    union { float f; unsigned int u; } v; v.f = f;
    unsigned int r = (v.u + 0x7fffu + ((v.u >> 16) & 1u)) >> 16;
    return (u16)r;
}

// packed f32x2 -> bf16x2 (RNE), one VALU op
__device__ __forceinline__ unsigned int cvtpk(float lo, float hi) {
    unsigned int r;
    asm("v_cvt_pk_bf16_f32 %0, %1, %2" : "=v"(r) : "v"(lo), "v"(hi));
    return r;
}

// async 16B global->LDS; lane i lands at (wave-uniform) dst + i*16.
__device__ __forceinline__ void gld16(const void* gsrc, void* ldst) {
    __builtin_amdgcn_global_load_lds(
        (const __attribute__((address_space(1))) unsigned int*)gsrc,
        (__attribute__((address_space(3))) unsigned int*)ldst, 16, 0, 0);
}

// additive seg swizzle for transpose-staged [row][64] u16 tiles
__device__ __forceinline__ int addsw(int seg, int s) {
    return (seg + (s & 7) + ((s >> 3) & 7)) & 7;
}

// ---------------------------------------------------------------- prep ----
__global__ __launch_bounds__(256) void prep_kernel(
    const float* __restrict__ wt, const float* __restrict__ wp,
    const float* __restrict__ wg, const float* __restrict__ wz,
    const float* __restrict__ g1, const float* __restrict__ b1,
    const float* __restrict__ m1, const float* __restrict__ v1,
    const float* __restrict__ g2, const float* __restrict__ b2,
    const float* __restrict__ m2, const float* __restrict__ v2,
    const float* __restrict__ g3, const float* __restrict__ b3,
    const float* __restrict__ m3, const float* __restrict__ v3,
    const float* __restrict__ g4, const float* __restrict__ b4,
    const float* __restrict__ m4, const float* __restrict__ v4,
    u16* __restrict__ W1bf, float* __restrict__ shift1,
    u16* __restrict__ Wzbf, float* __restrict__ shift4)
{
    int id = blockIdx.x * 256 + threadIdx.x;
    if (id < 384 * 256) {
        int r = id >> 8, c = id & 255;
        int grp = r >> 7, ch = r & 127;
        const float* wsrc = grp == 0 ? wt : (grp == 1 ? wp : wg);
        const float* gg = grp == 0 ? g1 : (grp == 1 ? g2 : g3);
        const float* bb = grp == 0 ? b1 : (grp == 1 ? b2 : b3);
        const float* mm = grp == 0 ? m1 : (grp == 1 ? m2 : m3);
        const float* vv = grp == 0 ? v1 : (grp == 1 ? v2 : v3);
        float scale = gg[ch] * rsqrtf(vv[ch] + BN_EPS);
        W1bf[id] = f2bf(wsrc[ch * 256 + c] * scale);
        if (c == 0) shift1[r] = bb[ch] - mm[ch] * scale;
    }
    if (id < 256 * 128) {
        int o = id >> 7;
        float scale = g4[o] * rsqrtf(v4[o] + BN_EPS);
        Wzbf[id] = f2bf(wz[id] * scale);
        if ((id & 127) == 0) shift4[o] = b4[o] - m4[o] * scale;
    }
}

// --------------------------------------------------------------- gemm1 ----
// One block computes ALL THREE projections (theta/phi/g) for a 64-pixel
// window: x chunk is converted+transposed into LDS ONCE, then contracted
// against all 384 W-rows (staged via gld16).  8 waves; wave w owns output
// rows  mt*128 + w*16 .. +16  for mt = 0,1,2  (acc[3][4] floatx4 = 48 VGPR).
__global__ __launch_bounds__(512, 4) void gemm1_kernel(
    const float* __restrict__ x, const u16* __restrict__ W1,
    const float* __restrict__ shift1,
    u16* __restrict__ theta_sm, u16* __restrict__ pg)
{
    const int st = blockIdx.x, n = blockIdx.y;
    const int tid = threadIdx.x;
    const int w = tid >> 6, lane = tid & 63;
    const int quad = lane >> 4, l16 = lane & 15;

    __shared__ __align__(16) u16 ldsA[384 * 64];  // W1 chunk (all 3 mt), xor-swizzled
    __shared__ __align__(16) u16 ldsB[64 * 64];   // x^T chunk [s][c], add-swizzled

    floatx4 acc[3][4];
#pragma unroll
    for (int i = 0; i < 3; ++i)
#pragma unroll
        for (int j = 0; j < 4; ++j) acc[i][j] = floatx4{0.f, 0.f, 0.f, 0.f};

    const int s4 = tid & 15;      // float4 index along s (64-s tile)
    const int cg = tid >> 4;      // channel pair 0..31
    const int slog = cg >> 2, dwin = cg & 3;
    const float* xb0 = x + ((size_t)n * 256 + 2 * cg) * 4096 + st * 64;
    unsigned int* ldsBdw = (unsigned int*)ldsB;

    float4 xv0 = *((const float4*)xb0 + s4);
    float4 xv1 = *((const float4*)(xb0 + 4096) + s4);

    for (int kc = 0; kc < 4; ++kc) {
        // --- write B tile from prefetched regs (cvt_pk packed, add-swizzled)
        const float* f0 = (const float*)&xv0;
        const float* f1 = (const float*)&xv1;
#pragma unroll
        for (int j = 0; j < 4; ++j) {
            int s = 4 * s4 + j;
            ldsBdw[s * 32 + addsw(slog, s) * 4 + dwin] = cvtpk(f0[j], f1[j]);
        }
        // --- async stage A: all 384 W-rows, cols kc*64..+64, xor seg swizzle
#pragma unroll
        for (int i = 0; i < 6; ++i) {
            int op = w * 6 + i;
            int r = op * 8 + (lane >> 3);
            int lseg = (lane & 7) ^ (r & 7);
            gld16(W1 + (size_t)r * 256 + kc * 64 + lseg * 8, ldsA + op * 512);
        }
        // --- prefetch next x chunk (drains with gld16 at the barrier)
        if (kc < 3) {
            xv0 = *((const float4*)(xb0 + (size_t)(kc + 1) * 64 * 4096) + s4);
            xv1 = *((const float4*)(xb0 + (size_t)((kc + 1) * 64 + 1) * 4096) + s4);
        }
        __syncthreads();

#pragma unroll
        for (int kk = 0; kk < 2; ++kk) {
            bf16x8 a[3];
#pragma unroll
            for (int mt = 0; mt < 3; ++mt) {
                int r = mt * 128 + w * 16 + l16;
                int phys = (kk * 4 + quad) ^ (r & 7);
                a[mt] = *(const bf16x8*)(ldsA + r * 64 + phys * 8);
            }
#pragma unroll
            for (int ni = 0; ni < 4; ++ni) {
                int s = ni * 16 + l16;
                int phys = addsw(kk * 4 + quad, s);
                bf16x8 b = *(const bf16x8*)(ldsB + s * 64 + phys * 8);
#pragma unroll
                for (int mt = 0; mt < 3; ++mt)
                    acc[mt][ni] = __builtin_amdgcn_mfma_f32_16x16x32_bf16(
                        a[mt], b, acc[mt][ni], 0, 0, 0);
            }
        }
        __syncthreads();
    }

    const int ocq = w * 16 + quad * 4;

    // theta (mt=0): write s-major [s][c], 8B vectorized
    {
        float sh0 = shift1[ocq + 0], sh1 = shift1[ocq + 1];
        float sh2 = shift1[ocq + 2], sh3 = shift1[ocq + 3];
#pragma unroll
        for (int ni = 0; ni < 4; ++ni) {
            int s = st * 64 + ni * 16 + l16;
            float v0 = acc[0][ni][0] + sh0, v1 = acc[0][ni][1] + sh1;
            float v2 = acc[0][ni][2] + sh2, v3 = acc[0][ni][3] + sh3;
            v0 = v0 > 0.f ? v0 : 0.f;
            v1 = v1 > 0.f ? v1 : 0.f;
            v2 = v2 > 0.f ? v2 : 0.f;
            v3 = v3 > 0.f ? v3 : 0.f;
            uint2 pk;
            pk.x = cvtpk(v0, v1);
            pk.y = cvtpk(v2, v3);
            *(uint2*)(theta_sm + (size_t)n * 524288 + (size_t)s * 128 + ocq) = pk;
        }
    }

    // phi/g (mt=1,2): row-major [oc'][s]
#pragma unroll
    for (int mt = 1; mt < 3; ++mt)
#pragma unroll
        for (int r = 0; r < 4; ++r) {
            int oc = mt * 128 + ocq + r;
            int prow = oc - 128;   // phi rows 0..127, g rows 128..255
            float sh = shift1[oc];
#pragma unroll
            for (int ni = 0; ni < 4; ++ni) {
                int s = st * 64 + ni * 16 + l16;
                float val = acc[mt][ni][r] + sh;
                val = val > 0.f ? val : 0.f;
                pg[(size_t)n * 1048576 + (size_t)prow * 4096 + s] = f2bf(val);
            }
        }
}

// --------------------------------------------------------------- gemm2 ----
// partials[n][kc][d][c] = sum_{s chunk} g[d][s]*phi[c][s]  (split-K=16)
// 512 threads (8 waves); gld16 staging of both operands.
__global__ __launch_bounds__(512) void gemm2_kernel(
    const u16* __restrict__ pg, float* __restrict__ partials)
{
    const int kc = blockIdx.x, n = blockIdx.y;
    const int tid = threadIdx.x;
    const int w = tid >> 6, lane = tid & 63;
    const int quad = lane >> 4, l16 = lane & 15;

    __shared__ __align__(16) u16 ldsG[128 * 64];  // g rows, xor-swizzled
    __shared__ __align__(16) u16 ldsP[128 * 64];  // phi rows, xor-swizzled

    floatx4 acc[2][4];
#pragma unroll
    for (int i = 0; i < 2; ++i)
#pragma unroll
        for (int j = 0; j < 4; ++j) acc[i][j] = floatx4{0.f, 0.f, 0.f, 0.f};

    const int d0 = (w >> 1) * 32, c0 = (w & 1) * 64;
    const u16* base = pg + (size_t)n * 1048576;   // phi rows 0..127, g 128..255

    for (int ch = 0; ch < 4; ++ch) {
        int s0 = kc * 256 + ch * 64;
#pragma unroll
        for (int i = 0; i < 2; ++i) {
            int op = w * 2 + i;
            int r = op * 8 + (lane >> 3);
            int lseg = (lane & 7) ^ (r & 7);
            gld16(base + (size_t)(128 + r) * 4096 + s0 + lseg * 8, ldsG + op * 512);
            gld16(base + (size_t)r * 4096 + s0 + lseg * 8, ldsP + op * 512);
        }
        __syncthreads();

#pragma unroll
        for (int kk = 0; kk < 2; ++kk) {
            bf16x8 a[2];
#pragma unroll
            for (int mi = 0; mi < 2; ++mi) {
                int r = d0 + mi * 16 + l16;
                int phys = (kk * 4 + quad) ^ (r & 7);
                a[mi] = *(const bf16x8*)(ldsG + r * 64 + phys * 8);
            }
#pragma unroll
            for (int ci = 0; ci < 4; ++ci) {
                int r = c0 + ci * 16 + l16;
                int phys = (kk * 4 + quad) ^ (r & 7);
                bf16x8 b = *(const bf16x8*)(ldsP + r * 64 + phys * 8);
#pragma unroll
                for (int mi = 0; mi < 2; ++mi)
                    acc[mi][ci] = __builtin_amdgcn_mfma_f32_16x16x32_bf16(
                        a[mi], b, acc[mi][ci], 0, 0, 0);
            }
        }
        __syncthreads();
    }

    float* outp = partials + (size_t)(n * 16 + kc) * 16384;
#pragma unroll
    for (int mi = 0; mi < 2; ++mi)
#pragma unroll
        for (int r = 0; r < 4; ++r) {
            int d = d0 + mi * 16 + quad * 4 + r;
#pragma unroll
            for (int ci = 0; ci < 4; ++ci)
                outp[d * 128 + c0 + ci * 16 + l16] = acc[mi][ci][r];
        }
}

// ----------------------------------------------------------- kv reduce ----
__global__ __launch_bounds__(256) void kv_reduce_kernel(
    const float* __restrict__ partials, u16* __restrict__ kvT)
{
    int n = blockIdx.y;
    int f4 = blockIdx.x * 256 + threadIdx.x;    // 0..4095
    const float4* p4 = (const float4*)partials;
    float4 s = {0.f, 0.f, 0.f, 0.f};
#pragma unroll
    for (int kc = 0; kc < 16; ++kc) {
        float4 v = p4[(size_t)(n * 16 + kc) * 4096 + f4];
        s.x += v.x; s.y += v.y; s.z += v.z; s.w += v.w;
    }
    u16x4 o; o[0] = f2bf(s.x); o[1] = f2bf(s.y); o[2] = f2bf(s.z); o[3] = f2bf(s.w);
    *(u16x4*)(kvT + (size_t)n * 16384 + f4 * 4) = o;
}

// --------------------------------------------------------------- gemm3 ----
// out_sd[n][s][d] = sum_c theta_sm[s][c] * kvT[d][c] — both k-major, pure gld16.
__global__ __launch_bounds__(256) void gemm3_kernel(
    const u16* __restrict__ theta_sm, const u16* __restrict__ kvT,
    u16* __restrict__ out_sd)
{
    const int st = blockIdx.x, n = blockIdx.y;
    const int tid = threadIdx.x;
    const int w = tid >> 6, lane = tid & 63;
    const int quad = lane >> 4, l16 = lane & 15;

    __shared__ __align__(16) u16 ldsT[128 * 64];  // theta [s][c], xor-swizzled
    __shared__ __align__(16) u16 ldsK[128 * 64];  // kvT [d][c], xor-swizzled

    floatx4 acc[2][8];
#pragma unroll
    for (int i = 0; i < 2; ++i)
#pragma unroll
        for (int j = 0; j < 8; ++j) acc[i][j] = floatx4{0.f, 0.f, 0.f, 0.f};

    const u16* tbase = theta_sm + (size_t)n * 524288 + (size_t)st * 128 * 128;
    const u16* kbase = kvT + (size_t)n * 16384;

    for (int ch = 0; ch < 2; ++ch) {
#pragma unroll
        for (int i = 0; i < 4; ++i) {
            int op = w * 4 + i;
            int r = op * 8 + (lane >> 3);
            int lseg = (lane & 7) ^ (r & 7);
            gld16(tbase + (size_t)r * 128 + ch * 64 + lseg * 8, ldsT + op * 512);
            gld16(kbase + (size_t)r * 128 + ch * 64 + lseg * 8, ldsK + op * 512);
        }
        __syncthreads();

#pragma unroll
        for (int kk = 0; kk < 2; ++kk) {
            bf16x8 a[2];
#pragma unroll
            for (int mi = 0; mi < 2; ++mi) {
                int r = w * 32 + mi * 16 + l16;
                int phys = (kk * 4 + quad) ^ (r & 7);
                a[mi] = *(const bf16x8*)(ldsT + r * 64 + phys * 8);
            }
#pragma unroll
            for (int di = 0; di < 8; ++di) {
                int r = di * 16 + l16;
                int phys = (kk * 4 + quad) ^ (r & 7);
                bf16x8 b = *(const bf16x8*)(ldsK + r * 64 + phys * 8);
#pragma unroll
                for (int mi = 0; mi < 2; ++mi)
                    acc[mi][di] = __builtin_amdgcn_mfma_f32_16x16x32_bf16(
                        a[mi], b, acc[mi][di], 0, 0, 0);
            }
        }
        __syncthreads();
    }

#pragma unroll
    for (int mi = 0; mi < 2; ++mi)
#pragma unroll
        for (int r = 0; r < 4; ++r) {
            int s = st * 128 + w * 32 + mi * 16 + quad * 4 + r;
#pragma unroll
            for (int di = 0; di < 8; ++di)
                out_sd[(size_t)n * 524288 + (size_t)s * 128 + di * 16 + l16] =
                    f2bf(acc[mi][di][r]);
        }
}

// --------------------------------------------------------------- gemm4 ----
// out[n][o][s2] = relu( sum_c2 Wz[o][c2]*y[c2][s2] + shift4[o] + x[n][o][s2] )
// y = out_sd viewed flat [128 c2][4096 s2]; y loads software-pipelined.
__global__ __launch_bounds__(256) void gemm4_kernel(
    const u16* __restrict__ out_sd, const u16* __restrict__ Wz,
    const float* __restrict__ shift4, const float* __restrict__ x,
    float* __restrict__ out)
{
    const int st = blockIdx.x, ot = blockIdx.y, n = blockIdx.z;
    const int tid = threadIdx.x;
    const int w = tid >> 6, lane = tid & 63;
    const int quad = lane >> 4, l16 = lane & 15;

    __shared__ __align__(16) u16 ldsY[128 * 64];  // y^T [s2][c2], add-swizzled
    __shared__ __align__(16) u16 ldsW[128 * 64];  // Wz [o][c2], xor-swizzled

    floatx4 acc[2][8];
#pragma unroll
    for (int i = 0; i < 2; ++i)
#pragma unroll
        for (int j = 0; j < 8; ++j) acc[i][j] = floatx4{0.f, 0.f, 0.f, 0.f};

    const int sl = tid & 15;
    const int cg = tid >> 4;
    const u16* ybase = out_sd + (size_t)n * 524288 + st * 128;
    unsigned int* ldsYdw = (unsigned int*)ldsY;

    u16x8 yv0[2], yv1[2];
#pragma unroll
    for (int p = 0; p < 2; ++p) {
        int c0 = 2 * cg + 32 * p;
        yv0[p] = *(const u16x8*)(ybase + (size_t)c0 * 4096 + 8 * sl);
        yv1[p] = *(const u16x8*)(ybase + (size_t)(c0 + 1) * 4096 + 8 * sl);
    }

    for (int kc = 0; kc < 2; ++kc) {
#pragma unroll
        for (int p = 0; p < 2; ++p) {
            int cp = cg + 16 * p, slog = cp >> 2, dwin = cp & 3;
#pragma unroll
            for (int j = 0; j < 8; ++j) {
                int s = 8 * sl + j;
                unsigned int pk = (unsigned int)yv0[p][j] | ((unsigned int)yv1[p][j] << 16);
                ldsYdw[s * 32 + addsw(slog, s) * 4 + dwin] = pk;
            }
        }
#pragma unroll
        for (int i = 0; i < 4; ++i) {
            int op = w * 4 + i;
            int r = op * 8 + (lane >> 3);
            int lseg = (lane & 7) ^ (r & 7);
            gld16(Wz + (size_t)(ot * 128 + r) * 128 + kc * 64 + lseg * 8, ldsW + op * 512);
        }
        if (kc < 1) {
#pragma unroll
            for (int p = 0; p < 2; ++p) {
                int c0 = 2 * cg + 32 * p;
                yv0[p] = *(const u16x8*)(ybase + (size_t)(64 + c0) * 4096 + 8 * sl);
                yv1[p] = *(const u16x8*)(ybase + (size_t)(64 + c0 + 1) * 4096 + 8 * sl);
            }
        }
        __syncthreads();

#pragma unroll
        for (int kk = 0; kk < 2; ++kk) {
            bf16x8 a[2];
#pragma unroll
            for (int mi = 0; mi < 2; ++mi) {
                int r = w * 32 + mi * 16 + l16;
                int phys = (kk * 4 + quad) ^ (r & 7);
                a[mi] = *(const bf16x8*)(ldsW + r * 64 + phys * 8);
            }
#pragma unroll
            for (int ni = 0; ni < 8; ++ni) {
                int s = ni * 16 + l16;
                int phys = addsw(kk * 4 + quad, s);
                bf16x8 b = *(const bf16x8*)(ldsY + s * 64 + phys * 8);
#pragma unroll
                for (int mi = 0; mi < 2; ++mi)
                    acc[mi][ni] = __builtin_amdgcn_mfma_f32_16x16x32_bf16(
                        a[mi], b, acc[mi][ni], 0, 0, 0);
            }
        }
        __syncthreads();
    }

#pragma unroll
    for (int mi = 0; mi < 2; ++mi)
#pragma unroll
        for (int r = 0; r < 4; ++r) {
            int o = ot * 128 + w * 32 + mi * 16 + quad * 4 + r;
            float sh = shift4[o];
#pragma unroll
            for (int ni = 0; ni < 8; ++ni) {
                int s2 = st * 128 + ni * 16 + l16;
                size_t idx = ((size_t)n * 256 + o) * 4096 + s2;
                float val = acc[mi][ni][r] + sh + x[idx];
                out[idx] = val > 0.f ? val : 0.f;
            }
        }
}

// -------------------------------------------------------------- launch ----
extern "C" void kernel_launch(void* const* d_in, const int* in_sizes, int n_in,
                              void* d_out, int out_size, void* d_ws, size_t ws_size,
                              hipStream_t stream)
{
    const float* x  = (const float*)d_in[0];
    const float* wt = (const float*)d_in[1];
    const float* wp = (const float*)d_in[2];
    const float* wg = (const float*)d_in[3];
    const float* wz = (const float*)d_in[4];
    const float* bn[16];
    for (int i = 0; i < 16; ++i) bn[i] = (const float*)d_in[5 + i];

    char* ws = (char*)d_ws;
    u16*   W1bf     = (u16*)  (ws + 0);          // 196608
    float* shift1   = (float*)(ws + 196608);     // 1536
    u16*   Wzbf     = (u16*)  (ws + 198144);     // 65536
    float* shift4   = (float*)(ws + 263680);     // 1024
    u16*   theta_sm = (u16*)  (ws + 264704);     // 16*4096*128*2 = 16777216
    u16*   pg       = (u16*)  (ws + 17041920);   // 16*256*4096*2 = 33554432
    float* partials = (float*)(ws + 50596352);   // 16*16*16384*4 = 16777216
    u16*   kvT      = (u16*)  (ws + 67373568);   // 524288
    u16*   out_sd   = (u16*)  (ws + 67897856);   // 16777216 (end 84.7MB)
    float* out = (float*)d_out;

    prep_kernel<<<384, 256, 0, stream>>>(
        wt, wp, wg, wz,
        bn[0], bn[1], bn[2], bn[3],
        bn[4], bn[5], bn[6], bn[7],
        bn[8], bn[9], bn[10], bn[11],
        bn[12], bn[13], bn[14], bn[15],
        W1bf, shift1, Wzbf, shift4);

    gemm1_kernel<<<dim3(64, 16), 512, 0, stream>>>(x, W1bf, shift1, theta_sm, pg);
    gemm2_kernel<<<dim3(16, 16), 512, 0, stream>>>(pg, partials);
    kv_reduce_kernel<<<dim3(16, 16), 256, 0, stream>>>(partials, kvT);
    gemm3_kernel<<<dim3(32, 16), 256, 0, stream>>>(theta_sm, kvT, out_sd);
    gemm4_kernel<<<dim3(32, 2, 16), 256, 0, stream>>>(out_sd, Wzbf, shift4, x, out);
}

// Round 2
// 215.777 us; speedup vs baseline: 1.0203x; 1.0203x over previous
//
#include <hip/hip_runtime.h>

#define BN_EPS 1e-5f

typedef unsigned short u16;
typedef __bf16 bf16x8 __attribute__((ext_vector_type(8)));
typedef float floatx4 __attribute__((ext_vector_type(4)));
typedef u16 u16x4 __attribute__((ext_vector_type(4)));
typedef u16 u16x8 __attribute__((ext_vector_type(8)));

__device__ __forceinline__ u16 f2bf(float f) {
    union { float f; unsigned int u; } v; v.f = f;
    unsigned int r = (v.u + 0x7fffu + ((v.u >> 16) & 1u)) >> 16;
    return (u16)r;
}

// packed f32x2 -> bf16x2 (RNE), one VALU op
__device__ __forceinline__ unsigned int cvtpk(float lo, float hi) {
    unsigned int r;
    asm("v_cvt_pk_bf16_f32 %0, %1, %2" : "=v"(r) : "v"(lo), "v"(hi));
    return r;
}

// async 16B global->LDS; lane i lands at (wave-uniform) dst + i*16.
__device__ __forceinline__ void gld16(const void* gsrc, void* ldst) {
    __builtin_amdgcn_global_load_lds(
        (const __attribute__((address_space(1))) unsigned int*)gsrc,
        (__attribute__((address_space(3))) unsigned int*)ldst, 16, 0, 0);
}

// additive seg swizzle for transpose-staged [row][64] u16 tiles
__device__ __forceinline__ int addsw(int seg, int s) {
    return (seg + (s & 7) + ((s >> 3) & 7)) & 7;
}

// ---------------------------------------------------------------- prep ----
__global__ __launch_bounds__(256) void prep_kernel(
    const float* __restrict__ wt, const float* __restrict__ wp,
    const float* __restrict__ wg, const float* __restrict__ wz,
    const float* __restrict__ g1, const float* __restrict__ b1,
    const float* __restrict__ m1, const float* __restrict__ v1,
    const float* __restrict__ g2, const float* __restrict__ b2,
    const float* __restrict__ m2, const float* __restrict__ v2,
    const float* __restrict__ g3, const float* __restrict__ b3,
    const float* __restrict__ m3, const float* __restrict__ v3,
    const float* __restrict__ g4, const float* __restrict__ b4,
    const float* __restrict__ m4, const float* __restrict__ v4,
    u16* __restrict__ W1bf, float* __restrict__ shift1,
    u16* __restrict__ Wzbf, float* __restrict__ shift4)
{
    int id = blockIdx.x * 256 + threadIdx.x;
    if (id < 384 * 256) {
        int r = id >> 8, c = id & 255;
        int grp = r >> 7, ch = r & 127;
        const float* wsrc = grp == 0 ? wt : (grp == 1 ? wp : wg);
        const float* gg = grp == 0 ? g1 : (grp == 1 ? g2 : g3);
        const float* bb = grp == 0 ? b1 : (grp == 1 ? b2 : b3);
        const float* mm = grp == 0 ? m1 : (grp == 1 ? m2 : m3);
        const float* vv = grp == 0 ? v1 : (grp == 1 ? v2 : v3);
        float scale = gg[ch] * rsqrtf(vv[ch] + BN_EPS);
        W1bf[id] = f2bf(wsrc[ch * 256 + c] * scale);
        if (c == 0) shift1[r] = bb[ch] - mm[ch] * scale;
    }
    if (id < 256 * 128) {
        int o = id >> 7;
        float scale = g4[o] * rsqrtf(v4[o] + BN_EPS);
        Wzbf[id] = f2bf(wz[id] * scale);
        if ((id & 127) == 0) shift4[o] = b4[o] - m4[o] * scale;
    }
}

// --------------------------------------------------------------- gemm1 ----
// All three projections per block over a 128-pixel window.  Double-buffered
// LDS (A: 2x48KB staged via gld16, B: 2x8KB x^T reg->LDS) with ONE barrier
// per K-step: stage(next) issued BEFORE compute(cur), x reg-loads issued a
// full iteration ahead (ping-pong xva/xvb) so the barrier drain waits on
// loads that already had a compute phase in flight.
__global__ __launch_bounds__(512, 2) void gemm1_kernel(
    const float* __restrict__ x, const u16* __restrict__ W1,
    const float* __restrict__ shift1,
    u16* __restrict__ theta_sm, u16* __restrict__ pg)
{
    const int st = blockIdx.x, n = blockIdx.y;
    const int tid = threadIdx.x;
    const int w = tid >> 6, lane = tid & 63;
    const int quad = lane >> 4, l16 = lane & 15;

    __shared__ __align__(16) u16 ldsA[2][384 * 64];  // 96 KB
    __shared__ __align__(16) u16 ldsB[2][128 * 64];  // 32 KB

    floatx4 acc[3][8];
#pragma unroll
    for (int i = 0; i < 3; ++i)
#pragma unroll
        for (int j = 0; j < 8; ++j) acc[i][j] = floatx4{0.f, 0.f, 0.f, 0.f};

    const int cp = w * 4 + quad;   // channel pair 0..31 (dwin = quad -> 2-way banks)
    const float* xb = x + ((size_t)n * 256 + 2 * cp) * 4096 + st * 128;

    float4 xva[2][2], xvb[2][2];   // [ch][s-half]

    auto loadx = [&](float4 (&xv)[2][2], int kc) {
#pragma unroll
        for (int ch = 0; ch < 2; ++ch)
#pragma unroll
            for (int hb = 0; hb < 2; ++hb)
                xv[ch][hb] = *((const float4*)(xb + (size_t)(kc * 64 + ch) * 4096) + hb * 16 + l16);
    };
    auto writeB = [&](int buf, const float4 (&xv)[2][2]) {
        unsigned int* bd = (unsigned int*)ldsB[buf];
#pragma unroll
        for (int hb = 0; hb < 2; ++hb)
#pragma unroll
            for (int j = 0; j < 4; ++j) {
                int s = hb * 64 + l16 * 4 + j;
                bd[s * 32 + addsw(w, s) * 4 + quad] =
                    cvtpk(((const float*)&xv[0][hb])[j], ((const float*)&xv[1][hb])[j]);
            }
    };
    auto stageA = [&](int buf, int kc) {
#pragma unroll
        for (int i = 0; i < 6; ++i) {
            int op = w * 6 + i;
            int r = op * 8 + (lane >> 3);
            int lseg = (lane & 7) ^ (r & 7);
            gld16(W1 + (size_t)r * 256 + kc * 64 + lseg * 8, ldsA[buf] + op * 512);
        }
    };
    auto compute = [&](int buf) {
#pragma unroll
        for (int kk = 0; kk < 2; ++kk) {
            bf16x8 a[3];
#pragma unroll
            for (int mt = 0; mt < 3; ++mt) {
                int r = mt * 128 + w * 16 + l16;
                int phys = (kk * 4 + quad) ^ (r & 7);
                a[mt] = *(const bf16x8*)(ldsA[buf] + r * 64 + phys * 8);
            }
#pragma unroll
            for (int ni = 0; ni < 8; ++ni) {
                int s = ni * 16 + l16;
                int phys = addsw(kk * 4 + quad, s);
                bf16x8 b = *(const bf16x8*)(ldsB[buf] + s * 64 + phys * 8);
#pragma unroll
                for (int mt = 0; mt < 3; ++mt)
                    acc[mt][ni] = __builtin_amdgcn_mfma_f32_16x16x32_bf16(
                        a[mt], b, acc[mt][ni], 0, 0, 0);
            }
        }
    };

    // prologue: fill buf0, issue kc=1 x loads
    loadx(xva, 0);
    stageA(0, 0);
    writeB(0, xva);
    loadx(xvb, 1);
    __syncthreads();

    // kc=0: compute buf0, stage kc1->buf1, issue x(kc2)
    loadx(xva, 2);
    stageA(1, 1);
    writeB(1, xvb);
    compute(0);
    __syncthreads();
    // kc=1
    loadx(xvb, 3);
    stageA(0, 2);
    writeB(0, xva);
    compute(1);
    __syncthreads();
    // kc=2
    stageA(1, 3);
    writeB(1, xvb);
    compute(0);
    __syncthreads();
    // kc=3
    compute(1);

    // -------- epilogue --------
    const int ocq = w * 16 + quad * 4;
    {
        float sh0 = shift1[ocq + 0], sh1 = shift1[ocq + 1];
        float sh2 = shift1[ocq + 2], sh3 = shift1[ocq + 3];
#pragma unroll
        for (int ni = 0; ni < 8; ++ni) {
            int s = st * 128 + ni * 16 + l16;
            float v0 = acc[0][ni][0] + sh0, v1 = acc[0][ni][1] + sh1;
            float v2 = acc[0][ni][2] + sh2, v3 = acc[0][ni][3] + sh3;
            v0 = v0 > 0.f ? v0 : 0.f;
            v1 = v1 > 0.f ? v1 : 0.f;
            v2 = v2 > 0.f ? v2 : 0.f;
            v3 = v3 > 0.f ? v3 : 0.f;
            uint2 pk;
            pk.x = cvtpk(v0, v1);
            pk.y = cvtpk(v2, v3);
            *(uint2*)(theta_sm + (size_t)n * 524288 + (size_t)s * 128 + ocq) = pk;
        }
    }
#pragma unroll
    for (int mt = 1; mt < 3; ++mt)
#pragma unroll
        for (int r = 0; r < 4; ++r) {
            int oc = mt * 128 + ocq + r;
            int prow = oc - 128;   // phi rows 0..127, g rows 128..255
            float sh = shift1[oc];
#pragma unroll
            for (int ni = 0; ni < 8; ++ni) {
                int s = st * 128 + ni * 16 + l16;
                float val = acc[mt][ni][r] + sh;
                val = val > 0.f ? val : 0.f;
                pg[(size_t)n * 1048576 + (size_t)prow * 4096 + s] = f2bf(val);
            }
        }
}

// --------------------------------------------------------------- gemm2 ----
// partials[n][kc][d][c] = sum_{s chunk} g[d][s]*phi[c][s]  (split-K=16)
// dbuf pipeline: stage(ch+1) issued before compute(ch), 1 barrier per chunk.
__global__ __launch_bounds__(512) void gemm2_kernel(
    const u16* __restrict__ pg, float* __restrict__ partials)
{
    const int kc = blockIdx.x, n = blockIdx.y;
    const int tid = threadIdx.x;
    const int w = tid >> 6, lane = tid & 63;
    const int quad = lane >> 4, l16 = lane & 15;

    __shared__ __align__(16) u16 ldsG[2][128 * 64];
    __shared__ __align__(16) u16 ldsP[2][128 * 64];

    floatx4 acc[2][4];
#pragma unroll
    for (int i = 0; i < 2; ++i)
#pragma unroll
        for (int j = 0; j < 4; ++j) acc[i][j] = floatx4{0.f, 0.f, 0.f, 0.f};

    const int d0 = (w >> 1) * 32, c0 = (w & 1) * 64;
    const u16* base = pg + (size_t)n * 1048576;   // phi rows 0..127, g 128..255

    auto stage = [&](int buf, int ch) {
        int s0 = kc * 256 + ch * 64;
#pragma unroll
        for (int i = 0; i < 2; ++i) {
            int op = w * 2 + i;
            int r = op * 8 + (lane >> 3);
            int lseg = (lane & 7) ^ (r & 7);
            gld16(base + (size_t)(128 + r) * 4096 + s0 + lseg * 8, ldsG[buf] + op * 512);
            gld16(base + (size_t)r * 4096 + s0 + lseg * 8, ldsP[buf] + op * 512);
        }
    };
    auto comp = [&](int buf) {
#pragma unroll
        for (int kk = 0; kk < 2; ++kk) {
            bf16x8 a[2];
#pragma unroll
            for (int mi = 0; mi < 2; ++mi) {
                int r = d0 + mi * 16 + l16;
                int phys = (kk * 4 + quad) ^ (r & 7);
                a[mi] = *(const bf16x8*)(ldsG[buf] + r * 64 + phys * 8);
            }
#pragma unroll
            for (int ci = 0; ci < 4; ++ci) {
                int r = c0 + ci * 16 + l16;
                int phys = (kk * 4 + quad) ^ (r & 7);
                bf16x8 b = *(const bf16x8*)(ldsP[buf] + r * 64 + phys * 8);
#pragma unroll
                for (int mi = 0; mi < 2; ++mi)
                    acc[mi][ci] = __builtin_amdgcn_mfma_f32_16x16x32_bf16(
                        a[mi], b, acc[mi][ci], 0, 0, 0);
            }
        }
    };

    stage(0, 0); __syncthreads();
    stage(1, 1); comp(0); __syncthreads();
    stage(0, 2); comp(1); __syncthreads();
    stage(1, 3); comp(0); __syncthreads();
    comp(1);

    float* outp = partials + (size_t)(n * 16 + kc) * 16384;
#pragma unroll
    for (int mi = 0; mi < 2; ++mi)
#pragma unroll
        for (int r = 0; r < 4; ++r) {
            int d = d0 + mi * 16 + quad * 4 + r;
#pragma unroll
            for (int ci = 0; ci < 4; ++ci)
                outp[d * 128 + c0 + ci * 16 + l16] = acc[mi][ci][r];
        }
}

// ----------------------------------------------------------- kv reduce ----
__global__ __launch_bounds__(256) void kv_reduce_kernel(
    const float* __restrict__ partials, u16* __restrict__ kvT)
{
    int n = blockIdx.y;
    int f4 = blockIdx.x * 256 + threadIdx.x;    // 0..4095
    const float4* p4 = (const float4*)partials;
    float4 s = {0.f, 0.f, 0.f, 0.f};
#pragma unroll
    for (int kc = 0; kc < 16; ++kc) {
        float4 v = p4[(size_t)(n * 16 + kc) * 4096 + f4];
        s.x += v.x; s.y += v.y; s.z += v.z; s.w += v.w;
    }
    u16x4 o; o[0] = f2bf(s.x); o[1] = f2bf(s.y); o[2] = f2bf(s.z); o[3] = f2bf(s.w);
    *(u16x4*)(kvT + (size_t)n * 16384 + f4 * 4) = o;
}

// --------------------------------------------------------------- gemm3 ----
// out_sd[n][s][d] = sum_c theta_sm[s][c] * kvT[d][c] — dbuf pipeline.
__global__ __launch_bounds__(256) void gemm3_kernel(
    const u16* __restrict__ theta_sm, const u16* __restrict__ kvT,
    u16* __restrict__ out_sd)
{
    const int st = blockIdx.x, n = blockIdx.y;
    const int tid = threadIdx.x;
    const int w = tid >> 6, lane = tid & 63;
    const int quad = lane >> 4, l16 = lane & 15;

    __shared__ __align__(16) u16 ldsT[2][128 * 64];
    __shared__ __align__(16) u16 ldsK[2][128 * 64];

    floatx4 acc[2][8];
#pragma unroll
    for (int i = 0; i < 2; ++i)
#pragma unroll
        for (int j = 0; j < 8; ++j) acc[i][j] = floatx4{0.f, 0.f, 0.f, 0.f};

    const u16* tbase = theta_sm + (size_t)n * 524288 + (size_t)st * 128 * 128;
    const u16* kbase = kvT + (size_t)n * 16384;

    auto stage = [&](int buf, int ch) {
#pragma unroll
        for (int i = 0; i < 4; ++i) {
            int op = w * 4 + i;
            int r = op * 8 + (lane >> 3);
            int lseg = (lane & 7) ^ (r & 7);
            gld16(tbase + (size_t)r * 128 + ch * 64 + lseg * 8, ldsT[buf] + op * 512);
            gld16(kbase + (size_t)r * 128 + ch * 64 + lseg * 8, ldsK[buf] + op * 512);
        }
    };
    auto comp = [&](int buf) {
#pragma unroll
        for (int kk = 0; kk < 2; ++kk) {
            bf16x8 a[2];
#pragma unroll
            for (int mi = 0; mi < 2; ++mi) {
                int r = w * 32 + mi * 16 + l16;
                int phys = (kk * 4 + quad) ^ (r & 7);
                a[mi] = *(const bf16x8*)(ldsT[buf] + r * 64 + phys * 8);
            }
#pragma unroll
            for (int di = 0; di < 8; ++di) {
                int r = di * 16 + l16;
                int phys = (kk * 4 + quad) ^ (r & 7);
                bf16x8 b = *(const bf16x8*)(ldsK[buf] + r * 64 + phys * 8);
#pragma unroll
                for (int mi = 0; mi < 2; ++mi)
                    acc[mi][di] = __builtin_amdgcn_mfma_f32_16x16x32_bf16(
                        a[mi], b, acc[mi][di], 0, 0, 0);
            }
        }
    };

    stage(0, 0); __syncthreads();
    stage(1, 1); comp(0); __syncthreads();
    comp(1);

#pragma unroll
    for (int mi = 0; mi < 2; ++mi)
#pragma unroll
        for (int r = 0; r < 4; ++r) {
            int s = st * 128 + w * 32 + mi * 16 + quad * 4 + r;
#pragma unroll
            for (int di = 0; di < 8; ++di)
                out_sd[(size_t)n * 524288 + (size_t)s * 128 + di * 16 + l16] =
                    f2bf(acc[mi][di][r]);
        }
}

// --------------------------------------------------------------- gemm4 ----
// out[n][o][s2] = relu( sum_c2 Wz[o][c2]*y[c2][s2] + shift4[o] + x[n][o][s2] )
// dbuf pipeline: stage W[1] + write Y[1] overlap compute(0).
__global__ __launch_bounds__(256) void gemm4_kernel(
    const u16* __restrict__ out_sd, const u16* __restrict__ Wz,
    const float* __restrict__ shift4, const float* __restrict__ x,
    float* __restrict__ out)
{
    const int st = blockIdx.x, ot = blockIdx.y, n = blockIdx.z;
    const int tid = threadIdx.x;
    const int w = tid >> 6, lane = tid & 63;
    const int quad = lane >> 4, l16 = lane & 15;

    __shared__ __align__(16) u16 ldsY[2][128 * 64];
    __shared__ __align__(16) u16 ldsW[2][128 * 64];

    floatx4 acc[2][8];
#pragma unroll
    for (int i = 0; i < 2; ++i)
#pragma unroll
        for (int j = 0; j < 8; ++j) acc[i][j] = floatx4{0.f, 0.f, 0.f, 0.f};

    const int sl = tid & 15;
    const int cg = tid >> 4;
    const u16* ybase = out_sd + (size_t)n * 524288 + st * 128;
    unsigned int* ldsYdw0 = (unsigned int*)ldsY[0];
    unsigned int* ldsYdw1 = (unsigned int*)ldsY[1];

    u16x8 ya0[2], ya1[2], yb0[2], yb1[2];

    auto loadY = [&](u16x8 (&y0)[2], u16x8 (&y1)[2], int kc) {
#pragma unroll
        for (int p = 0; p < 2; ++p) {
            int c0 = 2 * cg + 32 * p + kc * 64;
            y0[p] = *(const u16x8*)(ybase + (size_t)c0 * 4096 + 8 * sl);
            y1[p] = *(const u16x8*)(ybase + (size_t)(c0 + 1) * 4096 + 8 * sl);
        }
    };
    auto writeY = [&](unsigned int* yd, const u16x8 (&y0)[2], const u16x8 (&y1)[2]) {
#pragma unroll
        for (int p = 0; p < 2; ++p) {
            int cp = cg + 16 * p, slog = cp >> 2, dwin = cp & 3;
#pragma unroll
            for (int j = 0; j < 8; ++j) {
                int s = 8 * sl + j;
                yd[s * 32 + addsw(slog, s) * 4 + dwin] =
                    (unsigned int)y0[p][j] | ((unsigned int)y1[p][j] << 16);
            }
        }
    };
    auto stageW = [&](int buf, int kc) {
#pragma unroll
        for (int i = 0; i < 4; ++i) {
            int op = w * 4 + i;
            int r = op * 8 + (lane >> 3);
            int lseg = (lane & 7) ^ (r & 7);
            gld16(Wz + (size_t)(ot * 128 + r) * 128 + kc * 64 + lseg * 8, ldsW[buf] + op * 512);
        }
    };
    auto comp = [&](int buf) {
#pragma unroll
        for (int kk = 0; kk < 2; ++kk) {
            bf16x8 a[2];
#pragma unroll
            for (int mi = 0; mi < 2; ++mi) {
                int r = w * 32 + mi * 16 + l16;
                int phys = (kk * 4 + quad) ^ (r & 7);
                a[mi] = *(const bf16x8*)(ldsW[buf] + r * 64 + phys * 8);
            }
#pragma unroll
            for (int ni = 0; ni < 8; ++ni) {
                int s = ni * 16 + l16;
                int phys = addsw(kk * 4 + quad, s);
                bf16x8 b = *(const bf16x8*)(ldsY[buf] + s * 64 + phys * 8);
#pragma unroll
                for (int mi = 0; mi < 2; ++mi)
                    acc[mi][ni] = __builtin_amdgcn_mfma_f32_16x16x32_bf16(
                        a[mi], b, acc[mi][ni], 0, 0, 0);
            }
        }
    };

    loadY(ya0, ya1, 0);
    stageW(0, 0);
    writeY(ldsYdw0, ya0, ya1);
    loadY(yb0, yb1, 1);
    __syncthreads();

    stageW(1, 1);
    writeY(ldsYdw1, yb0, yb1);
    comp(0);
    __syncthreads();

    comp(1);

#pragma unroll
    for (int mi = 0; mi < 2; ++mi)
#pragma unroll
        for (int r = 0; r < 4; ++r) {
            int o = ot * 128 + w * 32 + mi * 16 + quad * 4 + r;
            float sh = shift4[o];
#pragma unroll
            for (int ni = 0; ni < 8; ++ni) {
                int s2 = st * 128 + ni * 16 + l16;
                size_t idx = ((size_t)n * 256 + o) * 4096 + s2;
                float val = acc[mi][ni][r] + sh + x[idx];
                out[idx] = val > 0.f ? val : 0.f;
            }
        }
}

// -------------------------------------------------------------- launch ----
extern "C" void kernel_launch(void* const* d_in, const int* in_sizes, int n_in,
                              void* d_out, int out_size, void* d_ws, size_t ws_size,
                              hipStream_t stream)
{
    const float* x  = (const float*)d_in[0];
    const float* wt = (const float*)d_in[1];
    const float* wp = (const float*)d_in[2];
    const float* wg = (const float*)d_in[3];
    const float* wz = (const float*)d_in[4];
    const float* bn[16];
    for (int i = 0; i < 16; ++i) bn[i] = (const float*)d_in[5 + i];

    char* ws = (char*)d_ws;
    u16*   W1bf     = (u16*)  (ws + 0);          // 196608
    float* shift1   = (float*)(ws + 196608);     // 1536
    u16*   Wzbf     = (u16*)  (ws + 198144);     // 65536
    float* shift4   = (float*)(ws + 263680);     // 1024
    u16*   theta_sm = (u16*)  (ws + 264704);     // 16*4096*128*2 = 16777216
    u16*   pg       = (u16*)  (ws + 17041920);   // 16*256*4096*2 = 33554432
    float* partials = (float*)(ws + 50596352);   // 16*16*16384*4 = 16777216
    u16*   kvT      = (u16*)  (ws + 67373568);   // 524288
    u16*   out_sd   = (u16*)  (ws + 67897856);   // 16777216 (end 84.7MB)
    float* out = (float*)d_out;

    prep_kernel<<<384, 256, 0, stream>>>(
        wt, wp, wg, wz,
        bn[0], bn[1], bn[2], bn[3],
        bn[4], bn[5], bn[6], bn[7],
        bn[8], bn[9], bn[10], bn[11],
        bn[12], bn[13], bn[14], bn[15],
        W1bf, shift1, Wzbf, shift4);

    gemm1_kernel<<<dim3(32, 16), 512, 0, stream>>>(x, W1bf, shift1, theta_sm, pg);
    gemm2_kernel<<<dim3(16, 16), 512, 0, stream>>>(pg, partials);
    kv_reduce_kernel<<<dim3(16, 16), 256, 0, stream>>>(partials, kvT);
    gemm3_kernel<<<dim3(32, 16), 256, 0, stream>>>(theta_sm, kvT, out_sd);
    gemm4_kernel<<<dim3(32, 2, 16), 256, 0, stream>>>(out_sd, Wzbf, shift4, x, out);
}